// Round 23
// baseline (51.499 us; speedup 1.0000x reference)
//
#include <hip/hip_runtime.h>

// (min,+) DP, wave-specialized. THREE images/block, 12 waves (768 thr),
// grid=ceil(512/3)=171 (1 blk/CU). Chains at wid 3,7,11 (wid%4==3 -> all
// on SIMD3): k=3 latency-bound chains interleave on one SIMD, filling each
// other's scan stalls (k=2 in R20 left SIMD3 at ~44% issue). 9 prep waves
// (3/image, 6/5/5 rows) on SIMD0-2. Chain row code = R20 verbatim
// (factored variants R21/R22 regressed: in-order issue means extra chain
// instructions cost more than the 1-DPP path saving).

#define HH 256
#define WW 256
#define CH 16          // rows per chunk
#define NCH 16         // chunks per image
#define NULLV 1e30f

template<int CTRL, int ROWM>
__device__ __forceinline__ float dpp_mov(float x, float oldv) {
    return __builtin_bit_cast(float, __builtin_amdgcn_update_dpp(
        __builtin_bit_cast(int, oldv), __builtin_bit_cast(int, x),
        CTRL, ROWM, 0xF, false));
}

// 64-lane inclusive min-scan: 6 fused in-place DPP steps.
__device__ __forceinline__ float wave_iscan_min(float x) {
    asm volatile(
        "s_nop 1\n\t"
        "v_min_f32_dpp %0, %0, %0 row_shr:1  row_mask:0xf bank_mask:0xf\n\t"
        "s_nop 1\n\t"
        "v_min_f32_dpp %0, %0, %0 row_shr:2  row_mask:0xf bank_mask:0xf\n\t"
        "s_nop 1\n\t"
        "v_min_f32_dpp %0, %0, %0 row_shr:4  row_mask:0xf bank_mask:0xf\n\t"
        "s_nop 1\n\t"
        "v_min_f32_dpp %0, %0, %0 row_shr:8  row_mask:0xf bank_mask:0xf\n\t"
        "s_nop 1\n\t"
        "v_min_f32_dpp %0, %0, %0 row_bcast:15 row_mask:0xa bank_mask:0xf\n\t"
        "s_nop 1\n\t"
        "v_min_f32_dpp %0, %0, %0 row_bcast:31 row_mask:0xc bank_mask:0xf"
        : "+v"(x));
    return x;
}

// 64-lane inclusive add-scan (prep only).
__device__ __forceinline__ float wave_iscan_add(float x) {
    asm volatile(
        "s_nop 1\n\t"
        "v_add_f32_dpp %0, %0, %0 row_shr:1  row_mask:0xf bank_mask:0xf bound_ctrl:0\n\t"
        "s_nop 1\n\t"
        "v_add_f32_dpp %0, %0, %0 row_shr:2  row_mask:0xf bank_mask:0xf bound_ctrl:0\n\t"
        "s_nop 1\n\t"
        "v_add_f32_dpp %0, %0, %0 row_shr:4  row_mask:0xf bank_mask:0xf bound_ctrl:0\n\t"
        "s_nop 1\n\t"
        "v_add_f32_dpp %0, %0, %0 row_shr:8  row_mask:0xf bank_mask:0xf bound_ctrl:0\n\t"
        "s_nop 1\n\t"
        "v_add_f32_dpp %0, %0, %0 row_bcast:15 row_mask:0xa bank_mask:0xf bound_ctrl:0\n\t"
        "s_nop 1\n\t"
        "v_add_f32_dpp %0, %0, %0 row_bcast:31 row_mask:0xc bank_mask:0xf bound_ctrl:0"
        : "+v"(x));
    return x;
}

__device__ __forceinline__ float softplus_f(float x) {
    float ax = fabsf(x);
    float t  = __expf(-ax);
    return fmaxf(x, 0.0f) + __logf(1.0f + t);
}

// full-row cumsum of softplus for one row; returns S at cols 4l..4l+3
__device__ __forceinline__ float4 prep_row(float4 c) {
    float t0 = softplus_f(c.x);
    float t1 = t0 + softplus_f(c.y);
    float t2 = t1 + softplus_f(c.z);
    float t3 = t2 + softplus_f(c.w);
    float s    = wave_iscan_add(t3);
    float soff = dpp_mov<0x138, 0xF>(s, 0.0f);  // wave_shr:1, lane0 -> 0
    return make_float4(soff + t0, soff + t1, soff + t2, soff + t3);
}

template<int NR>
__device__ __forceinline__ void load_rows(const float4* gp, int r0, float4* L) {
#pragma unroll
    for (int i = 0; i < NR; ++i) L[i] = gp[(size_t)(r0 + i) * 64];
}

template<int NR>
__device__ __forceinline__ void prep_store(const float4* L, float* dst, int lane) {
#pragma unroll
    for (int i = 0; i < NR; ++i)
        *reinterpret_cast<float4*>(&dst[i * WW + lane * 4]) = prep_row(L[i]);
}

template<int NR>
__device__ __forceinline__ void prep_run(const float4* gp, int row0,
                                         float* base0, float* base1, int lane) {
    float4 L[NR];
    load_rows<NR>(gp, CH + row0, L);           // chunk 1
    __syncthreads();                           // B0 (chunk 0 published by all)
    for (int k = 1; k < NCH; ++k) {
        float4 N[NR];
        if (k + 1 < NCH) load_rows<NR>(gp, (k + 1) * CH + row0, N);
        prep_store<NR>(L, (k & 1) ? base1 : base0, lane);
        __syncthreads();                       // Bk: chunk k ready
        if (k + 1 < NCH) {
#pragma unroll
            for (int i = 0; i < NR; ++i) L[i] = N[i];
        }
    }
}

__global__ __launch_bounds__(768, 1) void dp_kernel(const float* __restrict__ img,
                                                    float* __restrict__ out,
                                                    int nimg) {
    const int tid = threadIdx.x;
    const int wid = tid >> 6;                  // 0..11
    const int lane = tid & 63;

    // [slot][buffer][row][col] -> 96 KB
    __shared__ __align__(16) float sbuf[3][2][CH][WW];

    const bool is_chain = ((wid & 3) == 3);    // wid 3,7,11 -> SIMD3
    const int slot = is_chain ? (wid >> 2) : (wid & 3);       // 0..2
    const int pw   = is_chain ? -1 : (wid >> 2);              // 0..2
    int imgi = 3 * blockIdx.x + slot;
    if (imgi >= nimg) imgi = nimg - 1;         // clamp (dup write, same bits)
    const float* gbase = img + (size_t)imgi * HH * WW;
    const float4* gp = reinterpret_cast<const float4*>(gbase) + lane;

    if (is_chain) {
        // ---------------- chain wave (SIMD3, k=3 co-tenancy) ----------------
        {   // cooperative chunk-0: rows 0-3
            float4 C[4];
            load_rows<4>(gp, 0, C);
            prep_store<4>(C, &sbuf[slot][0][0][0], lane);
        }
        __syncthreads();                       // B0: chunk 0 ready
        __builtin_amdgcn_s_setprio(1);

        float v0, v1, v2, v3;
        auto row_step = [&](const float4& S) {
            float soff = dpp_mov<0x138, 0xF>(S.w, 0.0f);  // S[4l-1]
            float vm1  = dpp_mov<0x138, 0xF>(v3, NULLV);  // v[4l-1]
            float B0 = fminf(v0, vm1) - soff;
            float B1 = fminf(v1, v0) - S.x;
            float B2 = fminf(v2, v1) - S.y;
            float B3 = fminf(v3, v2) - S.z;
            float m1 = fminf(B0, B1);
            float p  = fminf(B2, B3);
            float m2 = fminf(m1, B2);
            float m3 = fminf(m1, p);           // depth-2 tree
            float mm   = wave_iscan_min(m3);   // fused DPP scan (asm)
            float moff = dpp_mov<0x138, 0xF>(mm, NULLV);
            v0 = S.x + fminf(moff, B0);
            v1 = S.y + fminf(moff, m1);
            v2 = S.z + fminf(moff, m2);
            v3 = S.w + fminf(moff, m3);
        };

#define RD8(P, buf, r0)                                                  \
    P##0 = *reinterpret_cast<const float4*>(&(buf)[(r0) + 0][lane * 4]); \
    P##1 = *reinterpret_cast<const float4*>(&(buf)[(r0) + 1][lane * 4]); \
    P##2 = *reinterpret_cast<const float4*>(&(buf)[(r0) + 2][lane * 4]); \
    P##3 = *reinterpret_cast<const float4*>(&(buf)[(r0) + 3][lane * 4]); \
    P##4 = *reinterpret_cast<const float4*>(&(buf)[(r0) + 4][lane * 4]); \
    P##5 = *reinterpret_cast<const float4*>(&(buf)[(r0) + 5][lane * 4]); \
    P##6 = *reinterpret_cast<const float4*>(&(buf)[(r0) + 6][lane * 4]); \
    P##7 = *reinterpret_cast<const float4*>(&(buf)[(r0) + 7][lane * 4]);
#define ST8(P)                                                           \
    row_step(P##0); row_step(P##1); row_step(P##2); row_step(P##3);      \
    row_step(P##4); row_step(P##5); row_step(P##6); row_step(P##7);

        float4 A0, A1, A2, A3, A4, A5, A6, A7;
        float4 B0, B1, B2, B3, B4, B5, B6, B7;

        // chunk 0 (rows 0..15; peel row-0 init)
        {
            const float(*buf)[WW] = sbuf[slot][0];
            RD8(A, buf, 0); RD8(B, buf, 8);
            v0 = A0.x; v1 = A0.y; v2 = A0.z; v3 = A0.w;
            row_step(A1); row_step(A2); row_step(A3);
            row_step(A4); row_step(A5); row_step(A6); row_step(A7);
            ST8(B);
        }
        // chunks 1..15
        for (int k = 1; k < NCH; ++k) {
            __syncthreads();                   // Bk
            const float(*buf)[WW] = sbuf[slot][k & 1];
            RD8(A, buf, 0); RD8(B, buf, 8);
            ST8(A);
            ST8(B);
        }
#undef RD8
#undef ST8
        if (lane == 63) out[imgi] = v3;
    } else {
        // ---------------- prep waves: 3 per image ----------------
        {   // cooperative chunk-0: rows 4+4pw .. 7+4pw
            float4 C[4];
            load_rows<4>(gp, 4 + 4 * pw, C);
            prep_store<4>(C, &sbuf[slot][0][4 + 4 * pw][0], lane);
        }
        const int row0 = (pw == 0) ? 0 : (pw == 1) ? 6 : 11;  // 6/5/5 rows
        float* b0 = &sbuf[slot][0][row0][0];
        float* b1 = &sbuf[slot][1][row0][0];
        if (pw == 0) prep_run<6>(gp, row0, b0, b1, lane);
        else         prep_run<5>(gp, row0, b0, b1, lane);
    }
}

extern "C" void kernel_launch(void* const* d_in, const int* in_sizes, int n_in,
                              void* d_out, int out_size, void* d_ws, size_t ws_size,
                              hipStream_t stream) {
    const float* img = (const float*)d_in[0];
    float* out = (float*)d_out;
    int nblocks = (out_size + 2) / 3;
    dp_kernel<<<nblocks, 768, 0, stream>>>(img, out, out_size);
}